// Round 6
// baseline (928.187 us; speedup 1.0000x reference)
//
#include <hip/hip_runtime.h>
#include <stdint.h>

#define BB 64
#define NN 1024
#define MM 1024
#define BPB 16                // blocks per batch
#define RPB (NN / BPB)        // 64 rows per block
#define RPW (RPB / 4)         // 16 rows per wave
#define NBLK (BB * BPB)       // 1024 persistent blocks (capacity 1280 at 5/CU)

typedef unsigned short u16;
typedef __attribute__((ext_vector_type(8))) unsigned short ushort8v;
typedef __attribute__((ext_vector_type(4))) float f32x4;

__device__ __forceinline__ float bf2f(u16 h) {
    union { uint32_t u; float f; } c; c.u = ((uint32_t)h) << 16; return c.f;
}
__device__ __forceinline__ u16 f2bf(float f) {
    union { float f; uint32_t u; } c; c.f = f;
    return (u16)((c.u + 0x7FFFu + ((c.u >> 16) & 1u)) >> 16);  // RNE
}

// Batch-local barrier (BPB blocks). Arrival: release RMW. Spin: RELAXED
// load + sleep (no per-iteration L2 invalidate). Exit: ONE acquire per
// block (thread 0, L1-invalidate is per-CU), then __syncthreads orders it
// before peer loads.
__device__ __forceinline__ void bat_bar(int* ctr, int target) {
    __syncthreads();
    if (threadIdx.x == 0) {
        __hip_atomic_fetch_add(ctr, 1, __ATOMIC_RELEASE, __HIP_MEMORY_SCOPE_AGENT);
        while (__hip_atomic_load(ctr, __ATOMIC_RELAXED, __HIP_MEMORY_SCOPE_AGENT) < target)
            __builtin_amdgcn_s_sleep(4);
        (void)__hip_atomic_load(ctr, __ATOMIC_ACQUIRE, __HIP_MEMORY_SCOPE_AGENT);
    }
    __syncthreads();
}

__global__ void k_init(int* c) {
    if (threadIdx.x < BB) c[threadIdx.x * 16] = 0;    // 64 batch counters
}

// Persistent producer: convert -> 7 fused sweeps -> v-combine into d_ws.
// Block (b, chunk) owns rows [chunk*64, chunk*64+64) of batch b; sbf reads
// are block-private. Only batch-local barriers.
__global__ __launch_bounds__(256, 5) void k_sink(
    const float* __restrict__ s, const float* __restrict__ temp,
    u16* __restrict__ sbf, float* __restrict__ p0, float* __restrict__ p1,
    float* __restrict__ vout, int* __restrict__ bar)
{
    __shared__ float sh[4][MM];                       // 16 KB, multi-use
    // Batch's 16 blocks share one blockIdx%8 class -> one XCD (L2 locality).
    const int b     = ((blockIdx.x & 7) << 3) | ((blockIdx.x >> 3) & 7);
    const int chunk = blockIdx.x >> 6;                // 0..15
    const int tid   = threadIdx.x;
    const int lane  = tid & 63;
    const int wv    = tid >> 6;
    const float invt = 1.0f / temp[0];
    int* mybar = bar + b * 16;                        // 64B-strided counters

    // ---- phase 1: f32 -> bf16 convert + initial col partials (u == 0)
    {
        const size_t base = ((size_t)b * NN + chunk * RPB) * MM + tid * 4;
        const float* sp = s + base;
        u16* op = sbf + base;
        float S0 = 0.f, S1 = 0.f, S2 = 0.f, S3 = 0.f;
        for (int r = 0; r < RPB; ++r) {
            f32x4 x = __builtin_nontemporal_load(      // stream s: no L3 alloc
                reinterpret_cast<const f32x4*>(sp + (size_t)r * MM));
            float a0 = x.x * invt, a1 = x.y * invt, a2 = x.z * invt, a3 = x.w * invt;
            ushort4 o; o.x = f2bf(a0); o.y = f2bf(a1); o.z = f2bf(a2); o.w = f2bf(a3);
            *reinterpret_cast<ushort4*>(op + (size_t)r * MM) = o;
            S0 += __expf(a0); S1 += __expf(a1); S2 += __expf(a2); S3 += __expf(a3);
        }
        *reinterpret_cast<float4*>(p0 + ((size_t)b * BPB + chunk) * MM + tid * 4)
            = make_float4(S0, S1, S2, S3);
    }
    bat_bar(mybar, BPB * 1);

    const float* psrc = p0;
    float*       pdst = p1;
    const u16* rp = sbf + ((size_t)b * NN + chunk * RPB + wv * RPW) * MM + lane * 16;

    // ---- 7 fused sweeps: combine v (redundant per block) + row-lse + col partials
    for (int p = 0; p < 7; ++p) {
        {   // combine: acc_j = sum of partials (= exp v_j), v_j = log(acc_j)
            const int c0 = tid * 4;
            float4 acc = make_float4(0.f, 0.f, 0.f, 0.f);
#pragma unroll
            for (int q = 0; q < BPB; ++q) {
                float4 pr = *reinterpret_cast<const float4*>(
                    psrc + ((size_t)b * BPB + q) * MM + c0);
                acc.x += pr.x; acc.y += pr.y; acc.z += pr.z; acc.w += pr.w;
            }
            float4 lv;
            lv.x = __logf(acc.x); lv.y = __logf(acc.y);
            lv.z = __logf(acc.z); lv.w = __logf(acc.w);
            *reinterpret_cast<float4*>(&sh[0][c0]) = lv;   // v
            *reinterpret_cast<float4*>(&sh[1][c0]) = acc;  // exp(v) for free
        }
        __syncthreads();
        float vv[16], ev[16];
#pragma unroll
        for (int q = 0; q < 4; ++q) {
            *reinterpret_cast<float4*>(&vv[q*4]) =
                *reinterpret_cast<const float4*>(&sh[0][lane*16 + q*4]);
            *reinterpret_cast<float4*>(&ev[q*4]) =
                *reinterpret_cast<const float4*>(&sh[1][lane*16 + q*4]);
        }
        __syncthreads();                                  // sh reused below

        float Sc[16];
#pragma unroll
        for (int k = 0; k < 16; ++k) Sc[k] = 0.f;

        // software-pipelined: stage row t+1 loads while computing row t
        ushort8v h0 = *reinterpret_cast<const ushort8v*>(rp);
        ushort8v h1 = *reinterpret_cast<const ushort8v*>(rp + 8);
#pragma unroll
        for (int t = 0; t < RPW; ++t) {
            ushort8v n0, n1;
            if (t + 1 < RPW) {
                n0 = *reinterpret_cast<const ushort8v*>(rp + (size_t)(t+1) * MM);
                n1 = *reinterpret_cast<const ushort8v*>(rp + (size_t)(t+1) * MM + 8);
            }
            float te[16];
#pragma unroll
            for (int k = 0; k < 8; ++k) te[k]     = __expf(bf2f(h0[k]) - vv[k]);
#pragma unroll
            for (int k = 0; k < 8; ++k) te[8 + k] = __expf(bf2f(h1[k]) - vv[8 + k]);
            float Sr = 0.f;
#pragma unroll
            for (int k = 0; k < 16; ++k) Sr += te[k];
#pragma unroll
            for (int off = 32; off >= 1; off >>= 1) Sr += __shfl_xor(Sr, off);
            const float w = __builtin_amdgcn_rcpf(Sr);    // 1/rowsum
#pragma unroll
            for (int k = 0; k < 16; ++k) Sc[k] = fmaf(te[k], w, Sc[k]);
            h0 = n0; h1 = n1;
        }
#pragma unroll
        for (int k = 0; k < 16; ++k) Sc[k] *= ev[k];      // row-independent factor

        // cross-wave reduce -> one partial row per block
#pragma unroll
        for (int q = 0; q < 4; ++q)
            *reinterpret_cast<float4*>(&sh[wv][lane*16 + q*4]) =
                *reinterpret_cast<float4*>(&Sc[q*4]);
        __syncthreads();
        {
            const int c0 = tid * 4;
            float4 a0 = *reinterpret_cast<float4*>(&sh[0][c0]);
            float4 a1 = *reinterpret_cast<float4*>(&sh[1][c0]);
            float4 a2 = *reinterpret_cast<float4*>(&sh[2][c0]);
            float4 a3 = *reinterpret_cast<float4*>(&sh[3][c0]);
            float4 r;
            r.x = (a0.x + a1.x) + (a2.x + a3.x);
            r.y = (a0.y + a1.y) + (a2.y + a3.y);
            r.z = (a0.z + a1.z) + (a2.z + a3.z);
            r.w = (a0.w + a1.w) + (a2.w + a3.w);
            *reinterpret_cast<float4*>(pdst + ((size_t)b * BPB + chunk) * MM + c0) = r;
        }
        bat_bar(mybar, BPB * (2 + p));
        const float* t2 = psrc; psrc = pdst; pdst = (float*)t2;
    }

    // ---- final v-combine (psrc == p1 after 7 swaps): one block per batch
    // writes v[b,:] into d_ws for the final kernel.
    if (chunk == 0) {
        const int c0 = tid * 4;
        float4 acc = make_float4(0.f, 0.f, 0.f, 0.f);
#pragma unroll
        for (int q = 0; q < BPB; ++q) {
            float4 pr = *reinterpret_cast<const float4*>(
                psrc + ((size_t)b * BPB + q) * MM + c0);
            acc.x += pr.x; acc.y += pr.y; acc.z += pr.z; acc.w += pr.w;
        }
        float4 lv;
        lv.x = __logf(acc.x); lv.y = __logf(acc.y);
        lv.z = __logf(acc.z); lv.w = __logf(acc.w);
        *reinterpret_cast<float4*>(vout + (size_t)b * MM + c0) = lv;
    }
}

// Final pass (separate kernel; stream order = global sync + d_out handover):
// out = exp(x)/rowsum, x = s/temp - v, full f32 source. Plain cached
// loads/stores (round-2-proven fast; nontemporal hints regressed 4x).
__global__ __launch_bounds__(256) void k_final(
    const float* __restrict__ s, const float* __restrict__ temp,
    const float* __restrict__ v, float* __restrict__ out)
{
    const int lane = threadIdx.x & 63;
    const int row  = blockIdx.x * 4 + (threadIdx.x >> 6);
    const int b    = row >> 10;
    const float invt = 1.0f / temp[0];
    const float* sp = s + (size_t)row * MM + lane * 16;
    const float* vp = v + (size_t)b * MM + lane * 16;
    float e[16];
    float S = 0.f;
#pragma unroll
    for (int q = 0; q < 4; ++q) {
        float4 xs = *reinterpret_cast<const float4*>(sp + q * 4);
        float4 vs = *reinterpret_cast<const float4*>(vp + q * 4);
        e[q*4+0] = __expf(xs.x * invt - vs.x);
        e[q*4+1] = __expf(xs.y * invt - vs.y);
        e[q*4+2] = __expf(xs.z * invt - vs.z);
        e[q*4+3] = __expf(xs.w * invt - vs.w);
        S += (e[q*4+0] + e[q*4+1]) + (e[q*4+2] + e[q*4+3]);
    }
#pragma unroll
    for (int off = 32; off >= 1; off >>= 1) S += __shfl_xor(S, off);
    const float w = 1.0f / S;
    float* op = out + (size_t)row * MM + lane * 16;
#pragma unroll
    for (int q = 0; q < 4; ++q) {
        float4 o;
        o.x = e[q*4+0] * w; o.y = e[q*4+1] * w;
        o.z = e[q*4+2] * w; o.w = e[q*4+3] * w;
        *reinterpret_cast<float4*>(op + q * 4) = o;
    }
}

extern "C" void kernel_launch(void* const* d_in, const int* in_sizes, int n_in,
                              void* d_out, int out_size, void* d_ws, size_t ws_size,
                              hipStream_t stream) {
    (void)in_sizes; (void)n_in; (void)out_size; (void)ws_size;
    const float* s    = (const float*)d_in[0];
    const float* temp = (const float*)d_in[1];
    float* out = (float*)d_out;

    // d_out layout: sbf bf16 copy [0,128MB) | p0 [128,132MB) | p1 [132,136MB)
    //   (read only inside k_sink; k_final overwrites d_out after the kernel
    //    boundary, so no overlap hazard)
    // d_ws layout: v [0, 256KB) | 64 barrier counters (64B stride), zeroed
    //   per call by k_init.
    u16*   sbf = (u16*)d_out;
    float* p0  = (float*)((char*)d_out + (size_t)BB * NN * MM * sizeof(u16));
    float* p1  = p0 + (size_t)BB * BPB * MM;
    float* v   = (float*)d_ws;
    int*   bar = (int*)((char*)d_ws + (size_t)BB * MM * sizeof(float));

    k_init<<<1, 128, 0, stream>>>(bar);
    k_sink<<<dim3(NBLK), dim3(256), 0, stream>>>(s, temp, sbf, p0, p1, v, bar);
    k_final<<<dim3(BB * NN / 4), dim3(256), 0, stream>>>(s, temp, v, out);
}

// Round 7
// 398.761 us; speedup vs baseline: 2.3277x; 2.3277x over previous
//
#include <hip/hip_runtime.h>
#include <stdint.h>

#define BB 64
#define NN 1024
#define MM 1024
#define CH 16            // row-chunks per batch == blocks per batch in sweeps

typedef unsigned short u16;
typedef __attribute__((ext_vector_type(8))) unsigned short ushort8v;

__device__ __forceinline__ float bf2f(u16 h) {
    union { uint32_t u; float f; } c; c.u = ((uint32_t)h) << 16; return c.f;
}
__device__ __forceinline__ u16 f2bf(float f) {
    union { float f; uint32_t u; } c; c.f = f;
    return (u16)((c.u + 0x7FFFu + ((c.u >> 16) & 1u)) >> 16);  // RNE
}

// Pass 0: read f32 s, write bf16 copy of s/temp, accumulate per-column
// plain sum-exp partials for the initial axis-1 logsumexp (u == 0).
// No-max is overflow-safe: |s/temp| <~ 6 -> exp <= 403, 64-row sum <= 26K.
__global__ __launch_bounds__(256) void k_convert(
    const float* __restrict__ s, const float* __restrict__ temp,
    u16* __restrict__ sbf, float* __restrict__ part)
{
    const int b     = blockIdx.x / CH;
    const int chunk = blockIdx.x % CH;
    const int col0  = threadIdx.x * 4;
    const float invt = 1.0f / temp[0];
    const int rows = NN / CH;                          // 64
    const size_t base = ((size_t)b * NN + (size_t)chunk * rows) * MM + col0;
    const float* sp = s + base;
    u16* op = sbf + base;
    float S0 = 0.f, S1 = 0.f, S2 = 0.f, S3 = 0.f;
    for (int r = 0; r < rows; ++r) {
        float4 x = *reinterpret_cast<const float4*>(sp + (size_t)r * MM);
        float a0 = x.x * invt, a1 = x.y * invt, a2 = x.z * invt, a3 = x.w * invt;
        ushort4 o; o.x = f2bf(a0); o.y = f2bf(a1); o.z = f2bf(a2); o.w = f2bf(a3);
        *reinterpret_cast<ushort4*>(op + (size_t)r * MM) = o;
        S0 += __expf(a0); S1 += __expf(a1); S2 += __expf(a2); S3 += __expf(a3);
    }
    *reinterpret_cast<float4*>(part + ((size_t)b * CH + chunk) * MM + col0) =
        make_float4(S0, S1, S2, S3);
}

// Fused sweep: per-block redundant combine of the previous pass's column
// partials (psrc -> v, exp(v) in LDS), then one pass over this block's 64
// rows of sbf performing BOTH the row update
//   u_i = log sum_j exp(sbf_ij - v_j)       (in-register, never stored)
// and the next col update's partials
//   Scol_j += exp(sbf_ij - u_i) = t_ij * exp(v_j) / Srow_i,
//   t_ij = exp(sbf_ij - v_j)   (one exp per element total).
// Kernel boundary = global sync; partials double-buffer psrc/pdst.
__global__ __launch_bounds__(256) void k_sweep(
    const u16* __restrict__ sbf, const float* __restrict__ psrc,
    float* __restrict__ pdst)
{
    __shared__ float sh[4][MM];                        // 16 KB, multi-use
    const int b     = blockIdx.x / CH;
    const int chunk = blockIdx.x % CH;
    const int tid   = threadIdx.x;
    const int lane  = tid & 63;
    const int wv    = tid >> 6;                        // 4 waves, 16 rows each

    {   // combine: acc_j = sum of 16 partials (= exp v_j), v_j = log(acc_j)
        const int c0 = tid * 4;
        float4 acc = make_float4(0.f, 0.f, 0.f, 0.f);
#pragma unroll
        for (int q = 0; q < CH; ++q) {
            float4 pr = *reinterpret_cast<const float4*>(
                psrc + ((size_t)b * CH + q) * MM + c0);
            acc.x += pr.x; acc.y += pr.y; acc.z += pr.z; acc.w += pr.w;
        }
        float4 lv;
        lv.x = __logf(acc.x); lv.y = __logf(acc.y);
        lv.z = __logf(acc.z); lv.w = __logf(acc.w);
        *reinterpret_cast<float4*>(&sh[0][c0]) = lv;   // v
        *reinterpret_cast<float4*>(&sh[1][c0]) = acc;  // exp(v) for free
    }
    __syncthreads();
    float vv[16], ev[16];
#pragma unroll
    for (int q = 0; q < 4; ++q) {
        *reinterpret_cast<float4*>(&vv[q*4]) =
            *reinterpret_cast<const float4*>(&sh[0][lane*16 + q*4]);
        *reinterpret_cast<float4*>(&ev[q*4]) =
            *reinterpret_cast<const float4*>(&sh[1][lane*16 + q*4]);
    }
    __syncthreads();                                   // sh reused below

    float Sc[16];
#pragma unroll
    for (int k = 0; k < 16; ++k) Sc[k] = 0.f;

    const int row0 = chunk * (NN / CH) + wv * 16;
    const u16* rp = sbf + ((size_t)b * NN + row0) * MM + lane * 16;
#pragma unroll 2
    for (int t = 0; t < 16; ++t) {                     // 16 rows per wave
        ushort8v h0 = *reinterpret_cast<const ushort8v*>(rp + (size_t)t * MM);
        ushort8v h1 = *reinterpret_cast<const ushort8v*>(rp + (size_t)t * MM + 8);
        float te[16];
#pragma unroll
        for (int k = 0; k < 8; ++k) te[k]     = __expf(bf2f(h0[k]) - vv[k]);
#pragma unroll
        for (int k = 0; k < 8; ++k) te[8 + k] = __expf(bf2f(h1[k]) - vv[8 + k]);
        float Sr = 0.f;
#pragma unroll
        for (int k = 0; k < 16; ++k) Sr += te[k];
#pragma unroll
        for (int off = 32; off >= 1; off >>= 1) Sr += __shfl_xor(Sr, off);
        const float w = __builtin_amdgcn_rcpf(Sr);     // 1/rowsum (~1 ulp)
#pragma unroll
        for (int k = 0; k < 16; ++k) Sc[k] = fmaf(te[k], w, Sc[k]);
    }
#pragma unroll
    for (int k = 0; k < 16; ++k) Sc[k] *= ev[k];       // row-independent factor

    // cross-wave reduce -> one partial row per block
#pragma unroll
    for (int q = 0; q < 4; ++q)
        *reinterpret_cast<float4*>(&sh[wv][lane*16 + q*4]) =
            *reinterpret_cast<float4*>(&Sc[q*4]);
    __syncthreads();
    {
        const int c0 = tid * 4;
        float4 a0 = *reinterpret_cast<float4*>(&sh[0][c0]);
        float4 a1 = *reinterpret_cast<float4*>(&sh[1][c0]);
        float4 a2 = *reinterpret_cast<float4*>(&sh[2][c0]);
        float4 a3 = *reinterpret_cast<float4*>(&sh[3][c0]);
        float4 r;
        r.x = (a0.x + a1.x) + (a2.x + a3.x);
        r.y = (a0.y + a1.y) + (a2.y + a3.y);
        r.z = (a0.z + a1.z) + (a2.z + a3.z);
        r.w = (a0.w + a1.w) + (a2.w + a3.w);
        *reinterpret_cast<float4*>(pdst + ((size_t)b * CH + chunk) * MM + c0) = r;
    }
}

// Combine the last sweep's partials -> v[b,j] = log(sum), into d_ws
// (outside d_out, because k_final overwrites all of d_out).
__global__ __launch_bounds__(256) void k_combine(
    const float* __restrict__ part, float* __restrict__ vout)
{
    const int idx = blockIdx.x * 256 + threadIdx.x;    // 0..BB*MM-1
    const int b = idx >> 10;
    const int j = idx & (MM - 1);
    float S = 0.f;
#pragma unroll
    for (int p = 0; p < CH; ++p) S += part[((size_t)b * CH + p) * MM + j];
    vout[idx] = __logf(S);
}

// Final pass: out = exp(x)/rowsum, x = s/temp - v, full f32 source.
// Plain cached loads/stores (nontemporal hints measured 4x slower here).
__global__ __launch_bounds__(256) void k_final(
    const float* __restrict__ s, const float* __restrict__ temp,
    const float* __restrict__ v, float* __restrict__ out)
{
    const int lane = threadIdx.x & 63;
    const int row  = blockIdx.x * 4 + (threadIdx.x >> 6);
    const int b    = row >> 10;
    const float invt = 1.0f / temp[0];
    const float* sp = s + (size_t)row * MM + lane * 16;
    const float* vp = v + (size_t)b * MM + lane * 16;
    float e[16];
    float S = 0.f;
#pragma unroll
    for (int q = 0; q < 4; ++q) {
        float4 xs = *reinterpret_cast<const float4*>(sp + q * 4);
        float4 vs = *reinterpret_cast<const float4*>(vp + q * 4);
        e[q*4+0] = __expf(xs.x * invt - vs.x);
        e[q*4+1] = __expf(xs.y * invt - vs.y);
        e[q*4+2] = __expf(xs.z * invt - vs.z);
        e[q*4+3] = __expf(xs.w * invt - vs.w);
        S += (e[q*4+0] + e[q*4+1]) + (e[q*4+2] + e[q*4+3]);
    }
#pragma unroll
    for (int off = 32; off >= 1; off >>= 1) S += __shfl_xor(S, off);
    const float w = 1.0f / S;
    float* op = out + (size_t)row * MM + lane * 16;
#pragma unroll
    for (int q = 0; q < 4; ++q) {
        float4 o;
        o.x = e[q*4+0] * w; o.y = e[q*4+1] * w;
        o.z = e[q*4+2] * w; o.w = e[q*4+3] * w;
        *reinterpret_cast<float4*>(op + q * 4) = o;
    }
}

extern "C" void kernel_launch(void* const* d_in, const int* in_sizes, int n_in,
                              void* d_out, int out_size, void* d_ws, size_t ws_size,
                              hipStream_t stream) {
    (void)in_sizes; (void)n_in; (void)out_size; (void)ws_size;
    const float* s    = (const float*)d_in[0];
    const float* temp = (const float*)d_in[1];
    float* out = (float*)d_out;

    // d_out layout: sbf bf16 copy [0,128MB) | p0 [128,132MB) | p1 [132,136MB)
    //   (all dead before k_final overwrites d_out; ordering via stream)
    // d_ws: v [0, 256KB) (k_final reads v while overwriting d_out).
    u16*   sbf = (u16*)d_out;
    float* p0  = (float*)((char*)d_out + (size_t)BB * NN * MM * sizeof(u16));
    float* p1  = p0 + (size_t)BB * CH * MM;
    float* v   = (float*)d_ws;

    dim3 blk(256);
    // initial axis-1 (column) normalization fused with f32->bf16 convert
    k_convert<<<dim3(BB * CH), blk, 0, stream>>>(s, temp, sbf, p0);
    // 7 fused sweeps (each = per-block combine + row update + col partials);
    // partials ping-pong p0 -> p1 -> p0 ...
    const float* ps = p0; float* pd = p1;
    for (int p = 0; p < 7; ++p) {
        k_sweep<<<dim3(BB * CH), blk, 0, stream>>>(sbf, ps, pd);
        const float* t2 = ps; ps = pd; pd = (float*)t2;
    }
    // combine last partials (ps == p1 after 7 swaps) -> v, then final pass
    k_combine<<<dim3(BB * MM / 256), blk, 0, stream>>>(ps, v);
    k_final<<<dim3(BB * NN / 4), blk, 0, stream>>>(s, temp, v, out);
}

// Round 8
// 389.710 us; speedup vs baseline: 2.3817x; 1.0232x over previous
//
#include <hip/hip_runtime.h>
#include <stdint.h>

#define BB 64
#define NN 1024
#define MM 1024
#define CH 16            // row-chunks per batch == blocks per batch in sweeps

typedef unsigned short u16;
typedef __attribute__((ext_vector_type(8))) unsigned short ushort8v;
typedef __attribute__((ext_vector_type(4))) float f32x4;

__device__ __forceinline__ float bf2f(u16 h) {
    union { uint32_t u; float f; } c; c.u = ((uint32_t)h) << 16; return c.f;
}
__device__ __forceinline__ u16 f2bf(float f) {
    union { float f; uint32_t u; } c; c.f = f;
    return (u16)((c.u + 0x7FFFu + ((c.u >> 16) & 1u)) >> 16);  // RNE
}

// Pass 0: read f32 s (NONTEMPORAL: read-once stream must not evict the
// 7x-reused sbf from L3), write bf16 copy of s/temp, accumulate per-column
// plain sum-exp partials for the initial axis-1 logsumexp (u == 0).
// No-max is overflow-safe: |s/temp| <~ 6 -> exp <= 403, 64-row sum <= 26K.
__global__ __launch_bounds__(256) void k_convert(
    const float* __restrict__ s, const float* __restrict__ temp,
    u16* __restrict__ sbf, float* __restrict__ part)
{
    const int b     = blockIdx.x / CH;
    const int chunk = blockIdx.x % CH;
    const int col0  = threadIdx.x * 4;
    const float invt = 1.0f / temp[0];
    const int rows = NN / CH;                          // 64
    const size_t base = ((size_t)b * NN + (size_t)chunk * rows) * MM + col0;
    const float* sp = s + base;
    u16* op = sbf + base;
    float S0 = 0.f, S1 = 0.f, S2 = 0.f, S3 = 0.f;
    for (int r = 0; r < rows; ++r) {
        f32x4 x = __builtin_nontemporal_load(
            reinterpret_cast<const f32x4*>(sp + (size_t)r * MM));
        float a0 = x.x * invt, a1 = x.y * invt, a2 = x.z * invt, a3 = x.w * invt;
        ushort4 o; o.x = f2bf(a0); o.y = f2bf(a1); o.z = f2bf(a2); o.w = f2bf(a3);
        *reinterpret_cast<ushort4*>(op + (size_t)r * MM) = o;   // plain store: allocate
        S0 += __expf(a0); S1 += __expf(a1); S2 += __expf(a2); S3 += __expf(a3);
    }
    *reinterpret_cast<float4*>(part + ((size_t)b * CH + chunk) * MM + col0) =
        make_float4(S0, S1, S2, S3);
}

// Fused sweep: per-block redundant combine of the previous pass's column
// partials (psrc -> v, exp(v) in LDS), then one pass over this block's 64
// rows of sbf performing BOTH the row update
//   u_i = log sum_j exp(sbf_ij - v_j)       (in-register, never stored)
// and the next col update's partials
//   Scol_j += exp(sbf_ij - u_i) = t_ij * exp(v_j) / Srow_i,
//   t_ij = exp(sbf_ij - v_j)   (one exp per element total).
// Kernel boundary = global sync; partials double-buffer psrc/pdst.
__global__ __launch_bounds__(256) void k_sweep(
    const u16* __restrict__ sbf, const float* __restrict__ psrc,
    float* __restrict__ pdst)
{
    __shared__ float sh[4][MM];                        // 16 KB, multi-use
    const int b     = blockIdx.x / CH;
    const int chunk = blockIdx.x % CH;
    const int tid   = threadIdx.x;
    const int lane  = tid & 63;
    const int wv    = tid >> 6;                        // 4 waves, 16 rows each

    {   // combine: acc_j = sum of 16 partials (= exp v_j), v_j = log(acc_j)
        const int c0 = tid * 4;
        float4 acc = make_float4(0.f, 0.f, 0.f, 0.f);
#pragma unroll
        for (int q = 0; q < CH; ++q) {
            float4 pr = *reinterpret_cast<const float4*>(
                psrc + ((size_t)b * CH + q) * MM + c0);
            acc.x += pr.x; acc.y += pr.y; acc.z += pr.z; acc.w += pr.w;
        }
        float4 lv;
        lv.x = __logf(acc.x); lv.y = __logf(acc.y);
        lv.z = __logf(acc.z); lv.w = __logf(acc.w);
        *reinterpret_cast<float4*>(&sh[0][c0]) = lv;   // v
        *reinterpret_cast<float4*>(&sh[1][c0]) = acc;  // exp(v) for free
    }
    __syncthreads();
    float vv[16], ev[16];
#pragma unroll
    for (int q = 0; q < 4; ++q) {
        *reinterpret_cast<float4*>(&vv[q*4]) =
            *reinterpret_cast<const float4*>(&sh[0][lane*16 + q*4]);
        *reinterpret_cast<float4*>(&ev[q*4]) =
            *reinterpret_cast<const float4*>(&sh[1][lane*16 + q*4]);
    }
    __syncthreads();                                   // sh reused below

    float Sc[16];
#pragma unroll
    for (int k = 0; k < 16; ++k) Sc[k] = 0.f;

    const int row0 = chunk * (NN / CH) + wv * 16;
    const u16* rp = sbf + ((size_t)b * NN + row0) * MM + lane * 16;
#pragma unroll 2
    for (int t = 0; t < 16; ++t) {                     // 16 rows per wave
        ushort8v h0 = *reinterpret_cast<const ushort8v*>(rp + (size_t)t * MM);
        ushort8v h1 = *reinterpret_cast<const ushort8v*>(rp + (size_t)t * MM + 8);
        float te[16];
#pragma unroll
        for (int k = 0; k < 8; ++k) te[k]     = __expf(bf2f(h0[k]) - vv[k]);
#pragma unroll
        for (int k = 0; k < 8; ++k) te[8 + k] = __expf(bf2f(h1[k]) - vv[8 + k]);
        float Sr = 0.f;
#pragma unroll
        for (int k = 0; k < 16; ++k) Sr += te[k];
#pragma unroll
        for (int off = 32; off >= 1; off >>= 1) Sr += __shfl_xor(Sr, off);
        const float w = __builtin_amdgcn_rcpf(Sr);     // 1/rowsum (~1 ulp)
#pragma unroll
        for (int k = 0; k < 16; ++k) Sc[k] = fmaf(te[k], w, Sc[k]);
    }
#pragma unroll
    for (int k = 0; k < 16; ++k) Sc[k] *= ev[k];       // row-independent factor

    // cross-wave reduce -> one partial row per block
#pragma unroll
    for (int q = 0; q < 4; ++q)
        *reinterpret_cast<float4*>(&sh[wv][lane*16 + q*4]) =
            *reinterpret_cast<float4*>(&Sc[q*4]);
    __syncthreads();
    {
        const int c0 = tid * 4;
        float4 a0 = *reinterpret_cast<float4*>(&sh[0][c0]);
        float4 a1 = *reinterpret_cast<float4*>(&sh[1][c0]);
        float4 a2 = *reinterpret_cast<float4*>(&sh[2][c0]);
        float4 a3 = *reinterpret_cast<float4*>(&sh[3][c0]);
        float4 r;
        r.x = (a0.x + a1.x) + (a2.x + a3.x);
        r.y = (a0.y + a1.y) + (a2.y + a3.y);
        r.z = (a0.z + a1.z) + (a2.z + a3.z);
        r.w = (a0.w + a1.w) + (a2.w + a3.w);
        *reinterpret_cast<float4*>(pdst + ((size_t)b * CH + chunk) * MM + c0) = r;
    }
}

// Combine the last sweep's partials -> v[b,j] = log(sum), into d_ws
// (outside d_out, because k_final overwrites all of d_out).
__global__ __launch_bounds__(256) void k_combine(
    const float* __restrict__ part, float* __restrict__ vout)
{
    const int idx = blockIdx.x * 256 + threadIdx.x;    // 0..BB*MM-1
    const int b = idx >> 10;
    const int j = idx & (MM - 1);
    float S = 0.f;
#pragma unroll
    for (int p = 0; p < CH; ++p) S += part[((size_t)b * CH + p) * MM + j];
    vout[idx] = __logf(S);
}

// Final pass: out = exp(x)/rowsum, x = s/temp - v, full f32 source.
// Plain cached loads/stores (nt stores measured 4x slower here; s-reads
// happen after all sweeps so L3 pollution no longer matters).
__global__ __launch_bounds__(256) void k_final(
    const float* __restrict__ s, const float* __restrict__ temp,
    const float* __restrict__ v, float* __restrict__ out)
{
    const int lane = threadIdx.x & 63;
    const int row  = blockIdx.x * 4 + (threadIdx.x >> 6);
    const int b    = row >> 10;
    const float invt = 1.0f / temp[0];
    const float* sp = s + (size_t)row * MM + lane * 16;
    const float* vp = v + (size_t)b * MM + lane * 16;
    float e[16];
    float S = 0.f;
#pragma unroll
    for (int q = 0; q < 4; ++q) {
        float4 xs = *reinterpret_cast<const float4*>(sp + q * 4);
        float4 vs = *reinterpret_cast<const float4*>(vp + q * 4);
        e[q*4+0] = __expf(xs.x * invt - vs.x);
        e[q*4+1] = __expf(xs.y * invt - vs.y);
        e[q*4+2] = __expf(xs.z * invt - vs.z);
        e[q*4+3] = __expf(xs.w * invt - vs.w);
        S += (e[q*4+0] + e[q*4+1]) + (e[q*4+2] + e[q*4+3]);
    }
#pragma unroll
    for (int off = 32; off >= 1; off >>= 1) S += __shfl_xor(S, off);
    const float w = 1.0f / S;
    float* op = out + (size_t)row * MM + lane * 16;
#pragma unroll
    for (int q = 0; q < 4; ++q) {
        float4 o;
        o.x = e[q*4+0] * w; o.y = e[q*4+1] * w;
        o.z = e[q*4+2] * w; o.w = e[q*4+3] * w;
        *reinterpret_cast<float4*>(op + q * 4) = o;
    }
}

extern "C" void kernel_launch(void* const* d_in, const int* in_sizes, int n_in,
                              void* d_out, int out_size, void* d_ws, size_t ws_size,
                              hipStream_t stream) {
    (void)in_sizes; (void)n_in; (void)out_size; (void)ws_size;
    const float* s    = (const float*)d_in[0];
    const float* temp = (const float*)d_in[1];
    float* out = (float*)d_out;

    // d_out layout: sbf bf16 copy [0,128MB) | p0 [128,132MB) | p1 [132,136MB)
    //   (all dead before k_final overwrites d_out; ordering via stream)
    // d_ws: v [0, 256KB) (k_final reads v while overwriting d_out).
    u16*   sbf = (u16*)d_out;
    float* p0  = (float*)((char*)d_out + (size_t)BB * NN * MM * sizeof(u16));
    float* p1  = p0 + (size_t)BB * CH * MM;
    float* v   = (float*)d_ws;

    dim3 blk(256);
    // initial axis-1 (column) normalization fused with f32->bf16 convert
    k_convert<<<dim3(BB * CH), blk, 0, stream>>>(s, temp, sbf, p0);
    // 7 fused sweeps (each = per-block combine + row update + col partials);
    // partials ping-pong p0 -> p1 -> p0 ...
    const float* ps = p0; float* pd = p1;
    for (int p = 0; p < 7; ++p) {
        k_sweep<<<dim3(BB * CH), blk, 0, stream>>>(sbf, ps, pd);
        const float* t2 = ps; ps = pd; pd = (float*)t2;
    }
    // combine last partials (ps == p1 after 7 swaps) -> v, then final pass
    k_combine<<<dim3(BB * MM / 256), blk, 0, stream>>>(ps, v);
    k_final<<<dim3(BB * NN / 4), blk, 0, stream>>>(s, temp, v, out);
}